// Round 2
// baseline (551.766 us; speedup 1.0000x reference)
//
#include <hip/hip_runtime.h>
#include <hip/hip_fp16.h>

#define N_ROWS 8191
#define NO 8092
#define GSTRIDE 8192
#define SEG 128
#define WARM 24

#define OUT_UU  65480464ul
#define OUT_KF  65488655ul
#define OUT_KDF 65496846ul

#define WS_XB   134217728ul
#define WS_DIAG 136314880ul
#define WS_Q    136347648ul

typedef short bf16x8 __attribute__((ext_vector_type(8)));
typedef float f32x4  __attribute__((ext_vector_type(4)));

__device__ __forceinline__ float h2f(unsigned short u) {
    __half_raw r; r.x = u; return __half2float(__half(r));
}

__device__ __forceinline__ float asin_core(float a) {
    float ax  = fabsf(a);
    bool  big = ax > 0.5f;
    float z   = big ? 0.5f * (1.0f - ax) : ax * ax;
    float x   = big ? __builtin_amdgcn_sqrtf(z) : ax;
    float p = fmaf(z, 4.2163199048e-2f, 2.4181311049e-2f);
    p = fmaf(p, z, 4.5470025998e-2f);
    p = fmaf(p, z, 7.4953002686e-2f);
    p = fmaf(p, z, 1.6666752422e-1f);
    p = fmaf(p * z, x, x);
    float r = big ? fmaf(-2.0f, p, 1.57079632679489662f) : p;
    return copysignf(r, a);
}

__device__ __forceinline__ float kstep(float g, float kp, float m) {
    float uv  = fmaf(0.5f, g, fmaf(0.9f, kp, 0.1f));
    float arg = uv * m;
    arg = fminf(fmaxf(arg, -0.999999f), 0.999999f);
    return 0.63661977236758134f * asin_core(arg);
}

__device__ __forceinline__ unsigned short f2bf(float f) {
    unsigned int u = __float_as_uint(f);
    u = (u + 0x7FFFu + ((u >> 16) & 1u)) >> 16;
    return (unsigned short)u;
}

// ---- kernel 1: X (fp32) -> Xb (bf16, zero-pad row 8191) + diag in one pass ----
__global__ void k_prep(const float* __restrict__ X, unsigned short* __restrict__ Xb,
                       float* __restrict__ diag) {
    int gw = (blockIdx.x * 256 + threadIdx.x) >> 6;   // row 0..8191
    int lane = threadIdx.x & 63;
    float2 v = make_float2(0.0f, 0.0f);
    if (gw < N_ROWS) v = ((const float2*)(X + (size_t)gw * 128))[lane];
    ushort2 b; b.x = f2bf(v.x); b.y = f2bf(v.y);
    ((ushort2*)(Xb + (size_t)gw * 128))[lane] = b;
    if (gw < N_ROWS) {
        float s = v.x * v.x + v.y * v.y;
        #pragma unroll
        for (int off = 32; off > 0; off >>= 1) s += __shfl_xor(s, off, 64);
        if (lane == 0) diag[gw] = s;
    }
}

// ---- kernel 2: diag scan -> uu, q (with padded tail), k_diag_final ----
__global__ void k_scan_diag(const float* __restrict__ diag, float* __restrict__ q,
                            float* __restrict__ d_out) {
    int tid = threadIdx.x;
    int t0  = tid * 32;
    int tw  = max(0, t0 - 32);
    int te  = min(t0 + 32, N_ROWS);
    float kp = 0.0f;
    for (int t = tw; t < te; ++t) {
        float dg = diag[t];
        float uv = fmaf(0.5f, dg, fmaf(0.9f, kp, 0.1f));
        float s  = fabsf(fmaf(2.0f, uv, 1.0f));
        float arg = (uv + uv) / s;
        arg = fminf(fmaxf(arg, -0.999999f), 0.999999f);
        float k = 0.63661977236758134f * asin_core(arg);
        if (t >= t0) {
            d_out[OUT_UU + t] = uv;
            q[t] = 1.0f / sqrtf(s);
            if (t == N_ROWS - 1) d_out[OUT_KDF] = k;
        }
        kp = k;
    }
    for (int j = tid; j < 1024; j += 256) q[N_ROWS + j] = 1.0f;  // pad tail
}

// ---- kernel 3: gramD[t][c] = <x_t, x_{t+c}> (bf16 MFMA, fp16 out, diag-major) ----
#define GP 136
__global__ __launch_bounds__(256) void k_gemm(const unsigned short* __restrict__ Xb,
                                              __half* __restrict__ gram) {
    int bi = blockIdx.y, bj = blockIdx.x;
    if (bj < bi) return;
    __shared__ short As[128 * GP];
    __shared__ short Bs[128 * GP];
    int tid = threadIdx.x;
    const uint4* ga = (const uint4*)(Xb + (size_t)bi * 128 * 128);
    const uint4* gb = (const uint4*)(Xb + (size_t)bj * 128 * 128);
    #pragma unroll
    for (int p = 0; p < 8; ++p) {
        int chunk = tid + p * 256;
        int row = chunk >> 4, c8 = chunk & 15;
        uint4 va = ga[row * 16 + c8];
        *(uint4*)&As[row * GP + c8 * 8] = va;
        uint4 vb = gb[row * 16 + c8];
        *(uint4*)&Bs[row * GP + c8 * 8] = vb;
    }
    __syncthreads();

    int lane = tid & 63, wave = tid >> 6;
    int wm = wave & 1, wn = wave >> 1;
    int lr = lane & 15, lk = lane >> 4;
    f32x4 acc[4][4];
    #pragma unroll
    for (int mi = 0; mi < 4; ++mi)
        #pragma unroll
        for (int ni = 0; ni < 4; ++ni) acc[mi][ni] = (f32x4){0.f, 0.f, 0.f, 0.f};

    #pragma unroll
    for (int kc = 0; kc < 4; ++kc) {
        bf16x8 a[4], b[4];
        #pragma unroll
        for (int mi = 0; mi < 4; ++mi)
            a[mi] = *(bf16x8*)&As[(wm * 64 + mi * 16 + lr) * GP + kc * 32 + lk * 8];
        #pragma unroll
        for (int ni = 0; ni < 4; ++ni)
            b[ni] = *(bf16x8*)&Bs[(wn * 64 + ni * 16 + lr) * GP + kc * 32 + lk * 8];
        #pragma unroll
        for (int mi = 0; mi < 4; ++mi)
            #pragma unroll
            for (int ni = 0; ni < 4; ++ni)
                acc[mi][ni] = __builtin_amdgcn_mfma_f32_16x16x32_bf16(a[mi], b[ni], acc[mi][ni], 0, 0, 0);
    }

    int row0 = (lane >> 4) * 4, col = lane & 15;
    #pragma unroll
    for (int mi = 0; mi < 4; ++mi) {
        #pragma unroll
        for (int ni = 0; ni < 4; ++ni) {
            int gi0 = bi * 128 + wm * 64 + mi * 16 + row0;
            int gj  = bj * 128 + wn * 64 + ni * 16 + col;
            f32x4 v = acc[mi][ni];
            #pragma unroll
            for (int r = 0; r < 4; ++r) {
                int gi = gi0 + r, c = gj - gi;
                if (c >= 0)
                    gram[(size_t)gi * GSTRIDE + c] = __float2half(v[r]);
            }
        }
    }
}

// ---- kernel 4: main scan — 4 diagonals per thread, 1-wave blocks ----
__global__ __launch_bounds__(64) void k_scan_main(const unsigned short* __restrict__ gram,
                                                  const float* __restrict__ q,
                                                  float* __restrict__ d_out) {
    int lane = threadIdx.x;
    int cbase = blockIdx.x * 256;
    int cl = cbase + lane * 4;
    int tlimw = N_ROWS - cbase;
    int t0 = 99 + blockIdx.y * SEG;
    if (t0 >= tlimw) return;
    int tend = min(t0 + SEG, tlimw);
    int tw = t0 - WARM;
    int tl0 = N_ROWS - cl;

    float k0 = 0.f, k1 = 0.f, k2 = 0.f, k3 = 0.f;
    float q0 = q[tw + cl], q1 = q[tw + cl + 1], q2 = q[tw + cl + 2], q3 = q[tw + cl + 3];
    const ushort4* gp = (const ushort4*)(gram + (size_t)tw * GSTRIDE + cl);

    for (int t = tw; t < t0; ++t) {
        ushort4 gv = *gp;
        float qt2 = q[t] * 2.0f;
        k0 = kstep(h2f(gv.x), k0, qt2 * q0);
        k1 = kstep(h2f(gv.y), k1, qt2 * q1);
        k2 = kstep(h2f(gv.z), k2, qt2 * q2);
        k3 = kstep(h2f(gv.w), k3, qt2 * q3);
        q0 = q1; q1 = q2; q2 = q3; q3 = q[t + cl + 4];
        gp += GSTRIDE / 4;
    }
    float* orow = d_out + (size_t)(t0 - 99) * NO + (t0 + cl - 99);
    if (tend + 256 <= tlimw) {
        // clean: all 4 elements active for every step
        for (int t = t0; t < tend; ++t) {
            ushort4 gv = *gp;
            float qt2 = q[t] * 2.0f;
            float g0 = h2f(gv.x), g1 = h2f(gv.y), g2 = h2f(gv.z), g3 = h2f(gv.w);
            k0 = kstep(g0, k0, qt2 * q0);
            k1 = kstep(g1, k1, qt2 * q1);
            k2 = kstep(g2, k2, qt2 * q2);
            k3 = kstep(g3, k3, qt2 * q3);
            orow[0] = fmaf(0.1f, g0, k0);
            orow[1] = fmaf(0.1f, g1, k1);
            orow[2] = fmaf(0.1f, g2, k2);
            orow[3] = fmaf(0.1f, g3, k3);
            q0 = q1; q1 = q2; q2 = q3; q3 = q[t + cl + 4];
            gp += GSTRIDE / 4; orow += NO + 1;
        }
    } else {
        for (int t = t0; t < tend; ++t) {
            ushort4 gv = *gp;
            float qt2 = q[t] * 2.0f;
            float g0 = h2f(gv.x), g1 = h2f(gv.y), g2 = h2f(gv.z), g3 = h2f(gv.w);
            k0 = kstep(g0, k0, qt2 * q0);
            k1 = kstep(g1, k1, qt2 * q1);
            k2 = kstep(g2, k2, qt2 * q2);
            k3 = kstep(g3, k3, qt2 * q3);
            if (t < tl0    ) orow[0] = fmaf(0.1f, g0, k0);
            if (t < tl0 - 1) orow[1] = fmaf(0.1f, g1, k1);
            if (t < tl0 - 2) orow[2] = fmaf(0.1f, g2, k2);
            if (t < tl0 - 3) orow[3] = fmaf(0.1f, g3, k3);
            if (t == tl0 - 1) d_out[OUT_KF + t] = k0;
            if (t == tl0 - 2) d_out[OUT_KF + t] = k1;
            if (t == tl0 - 3) d_out[OUT_KF + t] = k2;
            if (t == tl0 - 4) d_out[OUT_KF + t] = k3;
            q0 = q1; q1 = q2; q2 = q3; q3 = q[t + cl + 4];
            gp += GSTRIDE / 4; orow += NO + 1;
        }
    }
}

// ---- kernel 5: short diagonals (c >= 8092) feed k_final[0..98] exactly ----
__global__ void k_short_diag(const unsigned short* __restrict__ gram,
                             const float* __restrict__ q, float* __restrict__ d_out) {
    int l = threadIdx.x;
    if (l > 98) return;
    int c = NO + l;
    int tl = N_ROWS - c;
    float kp = 0.0f;
    for (int t = 0; t < tl; ++t) {
        float g = h2f(gram[(size_t)t * GSTRIDE + c]);
        float m = 2.0f * q[t] * q[t + c];
        kp = kstep(g, kp, m);
    }
    d_out[OUT_KF + (tl - 1)] = kp;
}

// ---- kernel 6: mirror upper -> strict lower, 64x64 float4 tiles ----
#define MT 64
__global__ __launch_bounds__(256) void k_mirror(float* __restrict__ out) {
    int tc = blockIdx.x, tr = blockIdx.y;
    if (tr < tc) return;
    __shared__ float tile[MT][MT + 1];
    int tid = threadIdx.x;
    int x4 = (tid & 15) * 4, yy = tid >> 4;
    int sr = tc * MT, scol = tr * MT;
    bool interior = (scol + MT <= NO);   // implies sr+MT<=NO since tc<=tr
    if (interior) {
        #pragma unroll
        for (int k = 0; k < 4; ++k) {
            int r = yy + 16 * k;
            float4 v = *(const float4*)&out[(size_t)(sr + r) * NO + scol + x4];
            tile[x4 + 0][r] = v.x; tile[x4 + 1][r] = v.y;
            tile[x4 + 2][r] = v.z; tile[x4 + 3][r] = v.w;
        }
    } else {
        for (int k = 0; k < 4; ++k) {
            int r = yy + 16 * k;
            for (int j = 0; j < 4; ++j) {
                int rr = sr + r, cc = scol + x4 + j;
                tile[x4 + j][r] = (rr < NO && cc < NO) ? out[(size_t)rr * NO + cc] : 0.0f;
            }
        }
    }
    __syncthreads();
    int dr = tr * MT, dcol = tc * MT;
    if (interior && tr != tc) {
        #pragma unroll
        for (int k = 0; k < 4; ++k) {
            int r = yy + 16 * k;
            float4 v;
            v.x = tile[r][x4 + 0]; v.y = tile[r][x4 + 1];
            v.z = tile[r][x4 + 2]; v.w = tile[r][x4 + 3];
            *(float4*)&out[(size_t)(dr + r) * NO + dcol + x4] = v;
        }
    } else {
        for (int k = 0; k < 4; ++k) {
            int r = yy + 16 * k;
            for (int j = 0; j < 4; ++j) {
                int rr = dr + r, cc = dcol + x4 + j;
                if (rr < NO && cc < NO && rr > cc)
                    out[(size_t)rr * NO + cc] = tile[r][x4 + j];
            }
        }
    }
}

extern "C" void kernel_launch(void* const* d_in, const int* in_sizes, int n_in,
                              void* d_out, int out_size, void* d_ws, size_t ws_size,
                              hipStream_t stream) {
    const float* X = (const float*)d_in[0];
    float* out = (float*)d_out;
    char* ws = (char*)d_ws;
    __half* gram = (__half*)ws;
    unsigned short* Xb = (unsigned short*)(ws + WS_XB);
    float* diag = (float*)(ws + WS_DIAG);
    float* q = (float*)(ws + WS_Q);

    k_prep<<<dim3(2048), dim3(256), 0, stream>>>(X, Xb, diag);
    k_scan_diag<<<dim3(1), dim3(256), 0, stream>>>(diag, q, out);
    k_gemm<<<dim3(64, 64), dim3(256), 0, stream>>>(Xb, gram);
    k_scan_main<<<dim3(32, 64), dim3(64), 0, stream>>>((const unsigned short*)gram, q, out);
    k_short_diag<<<dim3(1), dim3(128), 0, stream>>>((const unsigned short*)gram, q, out);
    k_mirror<<<dim3(127, 127), dim3(256), 0, stream>>>(out);
}